// Round 1
// baseline (32.125 us; speedup 1.0000x reference)
//
#include <hip/hip_runtime.h>

#define BB 4
#define NN 512
#define HH 64
#define NODES (BB*NN)

// ---------------- Kernel A: encoder MLP + message projections ----------------
// one wave (64 threads) per node; lane k owns output dim k.
__global__ __launch_bounds__(64) void enc_kernel(
    const float* __restrict__ pos,
    const float* __restrict__ enc_w1, const float* __restrict__ enc_b1,
    const float* __restrict__ enc_w2, const float* __restrict__ enc_b2,
    const float* __restrict__ msg_w1,
    float* __restrict__ h_out, float* __restrict__ ai_out, float* __restrict__ aj_out)
{
    const int node = blockIdx.x;
    const int k = threadIdx.x;
    __shared__ float t_s[HH];
    __shared__ float h_s[HH];

    const float px = pos[node*2+0];
    const float py = pos[node*2+1];

    // layer 1: relu(pos @ enc_w1 + enc_b1)
    float t = fmaf(px, enc_w1[k], fmaf(py, enc_w1[HH + k], enc_b1[k]));
    t_s[k] = fmaxf(t, 0.f);
    __syncthreads();

    // layer 2: h = t @ enc_w2 + enc_b2
    float h = enc_b2[k];
    #pragma unroll
    for (int m = 0; m < HH; ++m) h = fmaf(t_s[m], enc_w2[m*HH + k], h);
    h_s[k] = h;
    h_out[node*HH + k] = h;
    __syncthreads();

    // a_i = h @ msg_w1[:64],  a_j = h @ msg_w1[64:128]
    float ai = 0.f, aj = 0.f;
    #pragma unroll
    for (int m = 0; m < HH; ++m) {
        const float hm = h_s[m];
        ai = fmaf(hm, msg_w1[m*HH + k],        ai);
        aj = fmaf(hm, msg_w1[(HH + m)*HH + k], aj);
    }
    ai_out[node*HH + k] = ai;
    aj_out[node*HH + k] = aj;
}

// ---------------- Kernel B: pairwise relu-accumulate ----------------
// block = 256 threads = 4 waves; wave w handles node i = igrp*4 + w.
// All 4 waves stream the same A_j[b] panel -> L1 reuse.
// acc_k = sum_{j} relu(a_i_k + a_j[j]_k + d_ij * wd_k + b1_k), then subtract
// the exactly-reconstructible j==i term (d_ii = 0 exactly).
__global__ __launch_bounds__(256) void pair_kernel(
    const float* __restrict__ pos, const int* __restrict__ box_ptr,
    const float* __restrict__ msg_w1, const float* __restrict__ msg_b1,
    const float* __restrict__ ai, const float* __restrict__ aj,
    float* __restrict__ acc_out)
{
    const int w = threadIdx.x >> 6;
    const int k = threadIdx.x & 63;
    const int b = blockIdx.x >> 7;          // 128 i-groups per batch
    const int igrp = blockIdx.x & 127;
    const int i = igrp*4 + w;
    const int node = b*NN + i;

    const float box  = (float)box_ptr[0];
    const float hbox = 0.5f * box;

    __shared__ float dbuf[4][64];

    const float pix = pos[node*2+0];
    const float piy = pos[node*2+1];
    const float base = ai[node*HH + k] + msg_b1[k];
    const float wd   = msg_w1[2*HH*HH + k];

    float acc = 0.f;
    for (int jc = 0; jc < NN/64; ++jc) {
        // lane k computes the distance for j = jc*64 + k (own i)
        const int j = jc*64 + k;
        float dx = pos[(b*NN + j)*2 + 0] - pix;
        float dy = pos[(b*NN + j)*2 + 1] - piy;
        // minimum image: |dx| < box, so round(dx/box) in {-1,0,1};
        // strict compares at +/- box/2 match round-half-even.
        dx -= (dx >  hbox) ? box : 0.f;
        dx += (dx < -hbox) ? box : 0.f;
        dy -= (dy >  hbox) ? box : 0.f;
        dy += (dy < -hbox) ? box : 0.f;
        dbuf[w][k] = sqrtf(fmaf(dx, dx, dy*dy));
        __syncthreads();

        const float* ajp = aj + (size_t)(b*NN + jc*64)*HH + k;
        #pragma unroll
        for (int jj = 0; jj < 64; ++jj) {
            const float d   = dbuf[w][jj];       // uniform address -> broadcast
            const float ajk = ajp[jj*HH];        // coalesced across lanes
            const float t   = fmaf(d, wd, base + ajk);
            acc += fmaxf(t, 0.f);
        }
        __syncthreads();
    }
    // remove j == i contribution (d == 0 exactly -> same fp ops as in-loop)
    acc -= fmaxf(base + aj[node*HH + k], 0.f);
    acc_out[node*HH + k] = acc;
}

// ---------------- Kernel C: aggregate matmul + update MLP + decoder ----------------
// one wave per node; lane k owns dim k; LDS broadcast for the reduction dim.
__global__ __launch_bounds__(64) void out_kernel(
    const float* __restrict__ h_in, const float* __restrict__ acc_in,
    const float* __restrict__ msg_w2, const float* __restrict__ msg_b2,
    const float* __restrict__ upd_w1, const float* __restrict__ upd_b1,
    const float* __restrict__ upd_w2, const float* __restrict__ upd_b2,
    const float* __restrict__ dec_w1, const float* __restrict__ dec_b1,
    const float* __restrict__ dec_w2, const float* __restrict__ dec_b2,
    float* __restrict__ out)
{
    const int node = blockIdx.x;
    const int k = threadIdx.x;
    __shared__ float acc_s[HH], h_s[HH], agg_s[HH], p_s[HH], u_s[HH];

    acc_s[k] = acc_in[node*HH + k];
    h_s[k]   = h_in[node*HH + k];
    __syncthreads();

    // agg = (acc @ msg_w2) / (N-1) + msg_b2   (linearity: msg_b2 survives the mean)
    const float inv = 1.f / (float)(NN - 1);
    float agg = 0.f;
    #pragma unroll
    for (int m = 0; m < HH; ++m) agg = fmaf(acc_s[m], msg_w2[m*HH + k], agg);
    agg = fmaf(agg, inv, msg_b2[k]);
    agg_s[k] = agg;
    __syncthreads();

    // u = relu([h, agg] @ upd_w1 + upd_b1) @ upd_w2 + upd_b2
    float p = upd_b1[k];
    #pragma unroll
    for (int m = 0; m < HH; ++m) p = fmaf(h_s[m],   upd_w1[m*HH + k],        p);
    #pragma unroll
    for (int m = 0; m < HH; ++m) p = fmaf(agg_s[m], upd_w1[(HH + m)*HH + k], p);
    p_s[k] = fmaxf(p, 0.f);
    __syncthreads();

    float u = upd_b2[k];
    #pragma unroll
    for (int m = 0; m < HH; ++m) u = fmaf(p_s[m], upd_w2[m*HH + k], u);
    u_s[k] = u;
    __syncthreads();

    // forces = relu(u @ dec_w1 + dec_b1) @ dec_w2 + dec_b2
    float d1 = dec_b1[k];
    #pragma unroll
    for (int m = 0; m < HH; ++m) d1 = fmaf(u_s[m], dec_w1[m*HH + k], d1);
    d1 = fmaxf(d1, 0.f);

    float f0 = d1 * dec_w2[k*2 + 0];
    float f1 = d1 * dec_w2[k*2 + 1];
    #pragma unroll
    for (int off = 32; off >= 1; off >>= 1) {
        f0 += __shfl_xor(f0, off, 64);
        f1 += __shfl_xor(f1, off, 64);
    }
    if (k == 0) {
        out[node*2 + 0] = f0 + dec_b2[0];
        out[node*2 + 1] = f1 + dec_b2[1];
    }
}

extern "C" void kernel_launch(void* const* d_in, const int* in_sizes, int n_in,
                              void* d_out, int out_size, void* d_ws, size_t ws_size,
                              hipStream_t stream) {
    const float* pos    = (const float*)d_in[0];
    const int*   boxp   = (const int*)  d_in[1];
    const float* enc_w1 = (const float*)d_in[2];
    const float* enc_b1 = (const float*)d_in[3];
    const float* enc_w2 = (const float*)d_in[4];
    const float* enc_b2 = (const float*)d_in[5];
    const float* msg_w1 = (const float*)d_in[6];
    const float* msg_b1 = (const float*)d_in[7];
    const float* msg_w2 = (const float*)d_in[8];
    const float* msg_b2 = (const float*)d_in[9];
    const float* upd_w1 = (const float*)d_in[10];
    const float* upd_b1 = (const float*)d_in[11];
    const float* upd_w2 = (const float*)d_in[12];
    const float* upd_b2 = (const float*)d_in[13];
    const float* dec_w1 = (const float*)d_in[14];
    const float* dec_b1 = (const float*)d_in[15];
    const float* dec_w2 = (const float*)d_in[16];
    const float* dec_b2 = (const float*)d_in[17];

    float* ws  = (float*)d_ws;
    float* h   = ws;
    float* ai  = ws + (size_t)NODES*HH;
    float* aj  = ws + (size_t)2*NODES*HH;
    float* acc = ws + (size_t)3*NODES*HH;

    enc_kernel<<<NODES, 64, 0, stream>>>(pos, enc_w1, enc_b1, enc_w2, enc_b2,
                                         msg_w1, h, ai, aj);
    pair_kernel<<<NODES/4, 256, 0, stream>>>(pos, boxp, msg_w1, msg_b1, ai, aj, acc);
    out_kernel<<<NODES, 64, 0, stream>>>(h, acc, msg_w2, msg_b2,
                                         upd_w1, upd_b1, upd_w2, upd_b2,
                                         dec_w1, dec_b1, dec_w2, dec_b2,
                                         (float*)d_out);
}